// Round 4
// baseline (434.892 us; speedup 1.0000x reference)
//
#include <hip/hip_runtime.h>
#include <hip/hip_bf16.h>
#include <math.h>

#define BB   64
#define SS   512
#define NHH  4
#define DD   256
#define HH   256
#define LDH  264   // bf16 LDS row stride (halfwords)

typedef __attribute__((ext_vector_type(8))) short  short8;
typedef __attribute__((ext_vector_type(4))) float  floatx4;

// ---------------------------------------------------------------------------
// ws layout (floats):
//   [0,256)       v2[h]   = W2 @ (Wq @ w2)
//   [256,512)     cb1[h'] = (bk@Wproj + bproj)@W1b + b1   (xw1 bias, fully folded)
//   [512]         c2      = b2.v + bq.w2
//   [513]         ckw     = bk.w1
//   [768,1024)    qw[b*4+i] carried scalar state
//   [1024,1280)   wk1[h]  = Wk @ w1
//   [1280,1536)   bkp[j]  = bk@Wproj + bproj          (init temp)
//   [1536,1792)   vtmp[h] = Wq @ w2                   (init temp)
//   [1792,67328)  relu_u at t=511 (256 x 256 fp32)
//   [67328,132864)  Wfuse fp32 = Wproj@W1b            (init temp)
//   [132864,198400) Wkf   fp32 = Wk@Wfuse             (init temp)
//   [198400,263936) wpack: 2 mats x 65536 bf16 (Wkf, W1a) in B-frag layout
//   [263936,...)  chunk buffers x2: kw Tc*256 fp32 | xw1 Tc*65536 bf16 | kpw Tc*65536 bf16
// ---------------------------------------------------------------------------
#define OFF_V2     0
#define OFF_CB1    256
#define OFF_C2     512
#define OFF_CKW    513
#define OFF_QW     768
#define OFF_WK1    1024
#define OFF_BKP    1280
#define OFF_VT     1536
#define OFF_RU     1792
#define OFF_WFUSE  67328
#define OFF_WKF    132864
#define OFF_PACK   198400
#define OFF_CH     263936

__device__ __forceinline__ unsigned short f2b(float f) {
  __hip_bfloat16 h = __float2bfloat16(f);
  return __builtin_bit_cast(unsigned short, h);
}
__device__ __forceinline__ float b2f(unsigned short u) {
  unsigned v = (unsigned)u << 16;
  return __builtin_bit_cast(float, v);
}

// ---------------------------------------------------------------------------
// initA: blocks 0..255: Wfuse = Wproj @ W1b ; 256: bkp ; 257: vtmp = Wq@w2
// ---------------------------------------------------------------------------
__global__ __launch_bounds__(256) void initA_kernel(
    const float* __restrict__ Wproj, const float* __restrict__ W1,
    const float* __restrict__ bk, const float* __restrict__ bproj,
    const float* __restrict__ Wq, const float* __restrict__ w_mlp,
    float* __restrict__ ws)
{
  int tid = threadIdx.x;
  int bx = blockIdx.x;
  const float* W1b = W1 + 256 * 256;
  if (bx < 256) {
    __shared__ float row[256];
    row[tid] = Wproj[bx * 256 + tid];
    __syncthreads();
    float acc = 0.f;
#pragma unroll 8
    for (int k = 0; k < 256; ++k)
      acc = fmaf(row[k], W1b[k * 256 + tid], acc);
    ws[OFF_WFUSE + bx * 256 + tid] = acc;
  } else if (bx == 256) {
    float acc = bproj[tid];
#pragma unroll 8
    for (int k = 0; k < 256; ++k)
      acc = fmaf(bk[k], Wproj[k * 256 + tid], acc);
    ws[OFF_BKP + tid] = acc;
  } else {
    const float4* Wq4 = (const float4*)(Wq + tid * 256);
    const float4* w24 = (const float4*)(w_mlp + 256);
    float a = 0.f;
    for (int k = 0; k < 64; ++k) {
      float4 wv = Wq4[k], xv = w24[k];
      a = fmaf(wv.x, xv.x, fmaf(wv.y, xv.y, fmaf(wv.z, xv.z, fmaf(wv.w, xv.w, a))));
    }
    ws[OFF_VT + tid] = a;
  }
}

// ---------------------------------------------------------------------------
// initB: blocks 0..255: Wkf = Wk@Wfuse ; 256: cb1 ; 257: v2,c2,ckw,qw ; 258: wk1
// ---------------------------------------------------------------------------
__global__ __launch_bounds__(256) void initB_kernel(
    const float* __restrict__ Wk, const float* __restrict__ W1,
    const float* __restrict__ b1, const float* __restrict__ W2,
    const float* __restrict__ b2, const float* __restrict__ bq,
    const float* __restrict__ bk, const float* __restrict__ w_mlp,
    float* __restrict__ ws)
{
  int tid = threadIdx.x;
  int bx = blockIdx.x;
  if (bx < 256) {
    __shared__ float row[256];
    row[tid] = Wk[bx * 256 + tid];
    __syncthreads();
    float acc = 0.f;
    const float* Wf = ws + OFF_WFUSE;
#pragma unroll 8
    for (int k = 0; k < 256; ++k)
      acc = fmaf(row[k], Wf[k * 256 + tid], acc);
    ws[OFF_WKF + bx * 256 + tid] = acc;
  } else if (bx == 256) {
    const float* W1b = W1 + 256 * 256;
    float acc = b1[tid];
#pragma unroll 8
    for (int k = 0; k < 256; ++k)
      acc = fmaf(ws[OFF_BKP + k], W1b[k * 256 + tid], acc);
    ws[OFF_CB1 + tid] = acc;
  } else if (bx == 257) {
    __shared__ float red[256];
    // v2[h] = W2[h,:] . vtmp
    {
      const float4* W24 = (const float4*)(W2 + tid * 256);
      const float4* v4  = (const float4*)(ws + OFF_VT);
      float a = 0.f;
      for (int k = 0; k < 64; ++k) {
        float4 wv = W24[k], xv = v4[k];
        a = fmaf(wv.x, xv.x, fmaf(wv.y, xv.y, fmaf(wv.z, xv.z, fmaf(wv.w, xv.w, a))));
      }
      ws[OFF_V2 + tid] = a;
    }
    // s2 = bq.w2  -> qw init
    red[tid] = bq[tid] * w_mlp[256 + tid];
    __syncthreads();
    for (int s = 128; s; s >>= 1) { if (tid < s) red[tid] += red[tid + s]; __syncthreads(); }
    float s2 = red[0];
    __syncthreads();
    ws[OFF_QW + tid] = s2;
    // c2 = b2.vtmp + s2
    red[tid] = b2[tid] * ws[OFF_VT + tid];
    __syncthreads();
    for (int s = 128; s; s >>= 1) { if (tid < s) red[tid] += red[tid + s]; __syncthreads(); }
    if (tid == 0) ws[OFF_C2] = red[0] + s2;
    __syncthreads();
    // ckw = bk.w1
    red[tid] = bk[tid] * w_mlp[tid];
    __syncthreads();
    for (int s = 128; s; s >>= 1) { if (tid < s) red[tid] += red[tid + s]; __syncthreads(); }
    if (tid == 0) ws[OFF_CKW] = red[0];
  } else {
    // wk1[h] = Wk[h,:] . w1
    const float4* Wk4 = (const float4*)(Wk + tid * 256);
    const float4* w14 = (const float4*)(w_mlp);
    float a = 0.f;
    for (int k = 0; k < 64; ++k) {
      float4 wv = Wk4[k], xv = w14[k];
      a = fmaf(wv.x, xv.x, fmaf(wv.y, xv.y, fmaf(wv.z, xv.z, fmaf(wv.w, xv.w, a))));
    }
    ws[OFF_WK1 + tid] = a;
  }
}

// ---------------------------------------------------------------------------
// initC: pack Wkf (mat0, from ws fp32) and W1a (mat1) into MFMA B-frag bf16:
// wpack[mat][panel(16)][ks(8)][lane(64)][j(8)] = W[ks*32+(lane>>4)*8+j][panel*16+(lane&15)]
// ---------------------------------------------------------------------------
__global__ __launch_bounds__(256) void initC_kernel(
    const float* __restrict__ W1, float* __restrict__ ws)
{
  int idx = blockIdx.x * 256 + threadIdx.x;   // 0..131071
  int mat = idx >> 16;
  int rem = idx & 65535;
  int j    = rem & 7;
  int lane = (rem >> 3) & 63;
  int ks   = (rem >> 9) & 7;
  int pan  = rem >> 12;
  int k = ks * 32 + ((lane >> 4) << 3) + j;
  int n = pan * 16 + (lane & 15);
  float v = (mat == 0) ? ws[OFF_WKF + k * 256 + n] : W1[k * 256 + n];
  ((unsigned short*)(ws + OFF_PACK))[idx] = f2b(v);
}

// ---------------------------------------------------------------------------
// 64x256 (K=256) bf16 MFMA GEMM, 4x B-reuse: wave w owns n-panels [w*4,w*4+4),
// loops all 4 m-fragments from LDS. B prefetch +2; A single-buffered (LDS).
// ---------------------------------------------------------------------------
__device__ __forceinline__ void mfma_gemm4(
    const unsigned short* A_lds, const short8* __restrict__ Bp,
    const float* __restrict__ bias, floatx4 acc[4][4], int l, int w)
{
  int col = l & 15, quad = l >> 4;
#pragma unroll
  for (int pp = 0; pp < 4; ++pp) {
    float bv = bias ? bias[(w * 4 + pp) * 16 + col] : 0.f;
#pragma unroll
    for (int mf = 0; mf < 4; ++mf)
      acc[mf][pp] = (floatx4){bv, bv, bv, bv};
  }
  const short8* Bb = Bp + (size_t)(w * 4) * 512 + l;   // panel stride = 512 short8
  short8 bb[3][4];
#pragma unroll
  for (int pp = 0; pp < 4; ++pp) bb[0][pp] = Bb[pp * 512];
#pragma unroll
  for (int pp = 0; pp < 4; ++pp) bb[1][pp] = Bb[pp * 512 + 64];
#pragma unroll
  for (int kb = 0; kb < 8; ++kb) {
    if (kb + 2 < 8) {
#pragma unroll
      for (int pp = 0; pp < 4; ++pp)
        bb[(kb + 2) % 3][pp] = Bb[pp * 512 + (kb + 2) * 64];
    }
    short8 aa[4];
#pragma unroll
    for (int mf = 0; mf < 4; ++mf)
      aa[mf] = *(const short8*)(A_lds + (mf * 16 + col) * LDH + kb * 32 + quad * 8);
#pragma unroll
    for (int mf = 0; mf < 4; ++mf)
#pragma unroll
      for (int pp = 0; pp < 4; ++pp)
        acc[mf][pp] = __builtin_amdgcn_mfma_f32_16x16x32_bf16(
            aa[mf], bb[kb % 3][pp], acc[mf][pp], 0, 0, 0);
  }
}

// acc -> global bf16, layout [tc][b][head][256]
__device__ __forceinline__ void acc_to_global(
    unsigned short* __restrict__ dst, const floatx4 acc[4][4],
    int l, int w, int b, int tt)
{
  int col = l & 15, quad = l >> 4;
#pragma unroll
  for (int mf = 0; mf < 4; ++mf)
#pragma unroll
    for (int r = 0; r < 4; ++r) {
      int m2 = mf * 16 + quad * 4 + r;
      size_t base = (((size_t)(tt * 16 + (m2 >> 2)) * 64 + b) * 4 + (m2 & 3)) * 256;
#pragma unroll
      for (int pp = 0; pp < 4; ++pp)
        dst[base + (w * 4 + pp) * 16 + col] = f2b(acc[mf][pp][r]);
    }
}

// ---------------------------------------------------------------------------
__device__ void precompute_block(
    int px, const float* __restrict__ x, const float* __restrict__ ws,
    float* __restrict__ kw_c, unsigned short* __restrict__ xw1_c,
    unsigned short* __restrict__ kpw_c, int t0,
    float* kwbuf, unsigned short* XS)
{
  int b  = px & 63;
  int tt = px >> 6;
  int tid = threadIdx.x;
  int l = tid & 63, w = tid >> 6;

  // stage X (64x256 fp32 -> bf16 LDS), coalesced
  const float4* xsrc = (const float4*)(x + (size_t)(b * SS + t0 + tt * 16) * NHH * DD);
#pragma unroll
  for (int i = 0; i < 16; ++i) {
    int f4 = i * 256 + tid;
    int r = f4 >> 6, c4 = f4 & 63;
    float4 v = xsrc[f4];
    ushort4 h;
    h.x = f2b(v.x); h.y = f2b(v.y); h.z = f2b(v.z); h.w = f2b(v.w);
    *(ushort4*)&XS[r * LDH + c4 * 4] = h;
  }
  __syncthreads();

  const short8* wp0 = (const short8*)((const unsigned short*)(ws + OFF_PACK));          // Wkf
  const short8* wp1 = (const short8*)((const unsigned short*)(ws + OFF_PACK) + 65536);  // W1a

  // kw partial: wave w covers cols [w*64, w*64+64) of row l (fp32 acc, bf16 X)
  {
    float part = 0.f;
    const unsigned short* trow = XS + l * LDH + w * 64;
#pragma unroll
    for (int j8 = 0; j8 < 8; ++j8) {
      short8 tv = *(const short8*)(trow + j8 * 8);
#pragma unroll
      for (int j = 0; j < 8; ++j)
        part = fmaf(b2f((unsigned short)tv[j]), ws[OFF_WK1 + w * 64 + j8 * 8 + j], part);
    }
    kwbuf[l * 4 + w] = part;
  }

  floatx4 acc[4][4];

  // GEMM 1: kpw = X @ Wkf -> global bf16
  mfma_gemm4(XS, wp0, nullptr, acc, l, w);
  acc_to_global(kpw_c, acc, l, w, b, tt);
  __syncthreads();   // kwbuf complete

  if (tid < 64) {
    float s = kwbuf[tid * 4] + kwbuf[tid * 4 + 1] + kwbuf[tid * 4 + 2] + kwbuf[tid * 4 + 3]
            + ws[OFF_CKW];
    kw_c[((size_t)(tt * 16 + (tid >> 2)) * 64 + b) * 4 + (tid & 3)] = s;
  }

  // GEMM 2: xw1 = X @ W1a + cb1 -> global bf16
  mfma_gemm4(XS, wp1, ws + OFF_CB1, acc, l, w);
  acc_to_global(xw1_c, acc, l, w, b, tt);
}

// ---------------------------------------------------------------------------
__device__ __forceinline__ float wave_reduce_sum(float x) {
#define DPPSTEP(ctrl, rmask)                                                   \
  {                                                                            \
    int _s = __builtin_amdgcn_update_dpp(0, __builtin_bit_cast(int, x),        \
                                         (ctrl), (rmask), 0xf, true);          \
    x += __builtin_bit_cast(float, _s);                                        \
  }
  DPPSTEP(0x111, 0xf)   // row_shr:1
  DPPSTEP(0x112, 0xf)   // row_shr:2
  DPPSTEP(0x114, 0xf)   // row_shr:4
  DPPSTEP(0x118, 0xf)   // row_shr:8
  DPPSTEP(0x142, 0xa)   // row_bcast15
  DPPSTEP(0x143, 0xc)   // row_bcast31
#undef DPPSTEP
  return __builtin_bit_cast(float, __builtin_amdgcn_readlane(__builtin_bit_cast(int, x), 63));
}

__device__ __forceinline__ float tanh_fast(float y) {
  float ex = __expf(2.f * y);
  return 1.f - 2.f * __builtin_amdgcn_rcpf(ex + 1.f);
}

// ---------------------------------------------------------------------------
__device__ void seq_block(
    const unsigned short* __restrict__ xw1_c, const unsigned short* __restrict__ kpw_c,
    const float* __restrict__ kw_c, float* __restrict__ ws,
    float* __restrict__ relu_u, int t0, int n)
{
  int b = blockIdx.x;
  int tid = threadIdx.x;
  int i = tid >> 6, l = tid & 63;

  float4 v2v = ((const float4*)(ws + OFF_V2))[l];
  float c2 = ws[OFF_C2];
  float qw = ws[OFF_QW + b * 4 + i];

  const ushort4* xw = (const ushort4*)xw1_c;
  const ushort4* kp = (const ushort4*)kpw_c;

  struct Slot { ushort4 x, k0, k1, k2, k3; float4 kw; };

  auto load = [&](Slot& s, int tc) {
    size_t rb_ = (size_t)(tc * 64 + b) * 4;
    s.x  = xw[(rb_ + i) * 64 + l];
    s.k0 = kp[(rb_ + 0) * 64 + l];
    s.k1 = kp[(rb_ + 1) * 64 + l];
    s.k2 = kp[(rb_ + 2) * 64 + l];
    s.k3 = kp[(rb_ + 3) * 64 + l];
    s.kw = *(const float4*)&kw_c[rb_];
  };

  auto step = [&](Slot& s, int t) {
    float e0 = tanh_fast(qw + s.kw.x);
    float e1 = tanh_fast(qw + s.kw.y);
    float e2 = tanh_fast(qw + s.kw.z);
    float e3 = tanh_fast(qw + s.kw.w);
    float q0 = __expf(e0), q1 = __expf(e1), q2 = __expf(e2), q3 = __expf(e3);
    float inv = __builtin_amdgcn_rcpf(q0 + q1 + q2 + q3);
    float4 K0 = {b2f(s.k0.x), b2f(s.k0.y), b2f(s.k0.z), b2f(s.k0.w)};
    float4 K1 = {b2f(s.k1.x), b2f(s.k1.y), b2f(s.k1.z), b2f(s.k1.w)};
    float4 K2 = {b2f(s.k2.x), b2f(s.k2.y), b2f(s.k2.z), b2f(s.k2.w)};
    float4 K3 = {b2f(s.k3.x), b2f(s.k3.y), b2f(s.k3.z), b2f(s.k3.w)};
    float4 X  = {b2f(s.x.x), b2f(s.x.y), b2f(s.x.z), b2f(s.x.w)};
    float4 a;
    a.x = fmaf(q0, K0.x, fmaf(q1, K1.x, fmaf(q2, K2.x, q3 * K3.x)));
    a.y = fmaf(q0, K0.y, fmaf(q1, K1.y, fmaf(q2, K2.y, q3 * K3.y)));
    a.z = fmaf(q0, K0.z, fmaf(q1, K1.z, fmaf(q2, K2.z, q3 * K3.z)));
    a.w = fmaf(q0, K0.w, fmaf(q1, K1.w, fmaf(q2, K2.w, q3 * K3.w)));
    float4 u;
    u.x = fmaf(a.x, inv, X.x); u.y = fmaf(a.y, inv, X.y);
    u.z = fmaf(a.z, inv, X.z); u.w = fmaf(a.w, inv, X.w);
    float4 r;
    r.x = fmaxf(u.x, 0.f); r.y = fmaxf(u.y, 0.f);
    r.z = fmaxf(u.z, 0.f); r.w = fmaxf(u.w, 0.f);
    float d = fmaf(r.x, v2v.x, fmaf(r.y, v2v.y, fmaf(r.z, v2v.z, r.w * v2v.w)));
    qw = wave_reduce_sum(d) + c2;
    if (t0 + t == SS - 1)
      *(float4*)&relu_u[(size_t)(b * 4 + i) * 256 + l * 4] = r;
  };

  Slot s0, s1, s2, s3;
  load(s0, 0); load(s1, 1); load(s2, 2); load(s3, 3);
  for (int t = 0; t < n; t += 4) {
    int nt;
    step(s0, t);     nt = t + 4; load(s0, nt < n ? nt : n - 1);
    step(s1, t + 1); nt = t + 5; load(s1, nt < n ? nt : n - 1);
    step(s2, t + 2); nt = t + 6; load(s2, nt < n ? nt : n - 1);
    step(s3, t + 3); nt = t + 7; load(s3, nt < n ? nt : n - 1);
  }
  if (l == 0) ws[OFF_QW + b * 4 + i] = qw;
}

// ---------------------------------------------------------------------------
// Fused: blocks [0,64) = seq chunk (prev buffer), blocks [64,..) = precompute
// ---------------------------------------------------------------------------
__global__ __launch_bounds__(256, 3) void fused_kernel(
    const float* __restrict__ x,
    float* kwB, unsigned short* xw1B, unsigned short* kpwB, int t0_pre,
    const float* kwA, const unsigned short* xw1A, const unsigned short* kpwA,
    int t0_seq, int n_seq,
    float* __restrict__ ws, float* __restrict__ relu_u)
{
  __shared__ float kwbuf[256];
  __shared__ __align__(16) unsigned short XS[64 * LDH];
  if (blockIdx.x < 64) {
    if (n_seq > 0) seq_block(xw1A, kpwA, kwA, ws, relu_u, t0_seq, n_seq);
    return;
  }
  precompute_block(blockIdx.x - 64, x, ws, kwB, xw1B, kpwB, t0_pre, kwbuf, XS);
}

// ---------------------------------------------------------------------------
__global__ __launch_bounds__(256) void final_hidden_kernel(
    const float* __restrict__ relu_u, const float* __restrict__ W2,
    const float* __restrict__ b2, float* __restrict__ out)
{
  __shared__ float rs[256];
  int row = blockIdx.x;
  int tid = threadIdx.x;
  rs[tid] = relu_u[(size_t)row * 256 + tid];
  __syncthreads();
  float acc = b2[tid];
  for (int k = 0; k < 256; ++k) acc = fmaf(rs[k], W2[k * 256 + tid], acc);
  out[192 + (size_t)row * 256 + tid] = acc;
}

__global__ __launch_bounds__(256) void final_logits_kernel(
    const float* __restrict__ hf, const float* __restrict__ Wo,
    const float* __restrict__ bo, float* __restrict__ outp)
{
  __shared__ float r0[256], r1[256], r2[256];
  int b = blockIdx.x;
  int tid = threadIdx.x;
  float a0 = 0.f, a1 = 0.f, a2 = 0.f;
  for (int k = tid; k < 1024; k += 256) {
    float h = hf[(size_t)b * 1024 + k];
    a0 = fmaf(h, Wo[k * 3 + 0], a0);
    a1 = fmaf(h, Wo[k * 3 + 1], a1);
    a2 = fmaf(h, Wo[k * 3 + 2], a2);
  }
  r0[tid] = a0; r1[tid] = a1; r2[tid] = a2;
  __syncthreads();
  for (int s = 128; s; s >>= 1) {
    if (tid < s) { r0[tid] += r0[tid + s]; r1[tid] += r1[tid + s]; r2[tid] += r2[tid + s]; }
    __syncthreads();
  }
  if (tid == 0) {
    float l0 = r0[0] + bo[0], l1 = r1[0] + bo[1], l2 = r2[0] + bo[2];
    float m = fmaxf(l0, fmaxf(l1, l2));
    float lse = m + logf(expf(l0 - m) + expf(l1 - m) + expf(l2 - m));
    outp[b * 3 + 0] = l0 - lse;
    outp[b * 3 + 1] = l1 - lse;
    outp[b * 3 + 2] = l2 - lse;
  }
}

// ---------------------------------------------------------------------------
extern "C" void kernel_launch(void* const* d_in, const int* in_sizes, int n_in,
                              void* d_out, int out_size, void* d_ws, size_t ws_size,
                              hipStream_t stream)
{
  const float* x     = (const float*)d_in[0];
  const float* Wk    = (const float*)d_in[1];
  const float* bk    = (const float*)d_in[2];
  const float* Wq    = (const float*)d_in[3];
  const float* bq    = (const float*)d_in[4];
  const float* w_mlp = (const float*)d_in[5];
  const float* Wproj = (const float*)d_in[6];
  const float* bproj = (const float*)d_in[7];
  const float* W1    = (const float*)d_in[8];
  const float* b1    = (const float*)d_in[9];
  const float* W2    = (const float*)d_in[10];
  const float* b2    = (const float*)d_in[11];
  const float* Wo    = (const float*)d_in[12];
  const float* bo    = (const float*)d_in[13];
  float* out = (float*)d_out;
  float* ws  = (float*)d_ws;

  float* ru = ws + OFF_RU;
  const long per_t = 256 + 65536;   // kw fp32 + (xw1 + kpw) bf16, in float units

  long ws_floats = (long)(ws_size / 4);
  long avail = ws_floats - (long)OFF_CH;

  int Tc = 128;
  while (Tc > 0 && 2L * Tc * per_t > avail) Tc -= 16;
  bool pipelined = (Tc >= 16);
  if (!pipelined) {
    Tc = 128;
    while (Tc > 16 && (long)Tc * per_t > avail) Tc -= 16;
  }

  float* bufA = ws + OFF_CH;
  float* bufB = pipelined ? bufA + (size_t)Tc * per_t : bufA;

  auto kw_of  = [&](float* base) { return base; };
  auto xw_of  = [&](float* base) { return (unsigned short*)(base + (size_t)Tc * 256); };
  auto kpw_of = [&](float* base) { return (unsigned short*)(base + (size_t)Tc * 256) + (size_t)Tc * 65536; };

  initA_kernel<<<258, 256, 0, stream>>>(Wproj, W1, bk, bproj, Wq, w_mlp, ws);
  initB_kernel<<<259, 256, 0, stream>>>(Wk, W1, b1, W2, b2, bq, bk, w_mlp, ws);
  initC_kernel<<<512, 256, 0, stream>>>(W1, ws);

  int C = (SS + Tc - 1) / Tc;

  if (pipelined) {
    for (int r = 0; r <= C; ++r) {
      bool hasPre = (r < C);
      bool hasSeq = (r >= 1);
      int t0p = r * Tc;
      int np  = hasPre ? ((SS - t0p) < Tc ? (SS - t0p) : Tc) : 0;
      int t0s = (r - 1) * Tc;
      int ns  = hasSeq ? ((SS - t0s) < Tc ? (SS - t0s) : Tc) : 0;
      float* pB = ((r & 1) ? bufB : bufA);
      float* pA = (((r - 1) & 1) ? bufB : bufA);
      int grid = 64 + (hasPre ? 64 * (np / 16) : 0);
      fused_kernel<<<grid, 256, 0, stream>>>(
          x,
          kw_of(pB), xw_of(pB), kpw_of(pB), t0p,
          kw_of(pA), xw_of(pA), kpw_of(pA), t0s, ns,
          ws, ru);
    }
  } else {
    for (int c = 0; c < C; ++c) {
      int t0 = c * Tc;
      int n = (SS - t0) < Tc ? (SS - t0) : Tc;
      fused_kernel<<<64 + 64 * (n / 16), 256, 0, stream>>>(
          x,
          kw_of(bufA), xw_of(bufA), kpw_of(bufA), t0,
          kw_of(bufA), xw_of(bufA), kpw_of(bufA), 0, 0,
          ws, ru);
      fused_kernel<<<64, 256, 0, stream>>>(
          x,
          kw_of(bufA), xw_of(bufA), kpw_of(bufA), t0,
          kw_of(bufA), xw_of(bufA), kpw_of(bufA), t0, n,
          ws, ru);
    }
  }

  final_hidden_kernel<<<BB * NHH, 256, 0, stream>>>(ru, W2, b2, out);
  final_logits_kernel<<<BB, 256, 0, stream>>>(out + 192, Wo, bo, out);
}